// Round 4
// baseline (262.225 us; speedup 1.0000x reference)
//
#include <hip/hip_runtime.h>
#include <hip/hip_bf16.h>

// Problem constants
// B=64, N=256, IN=512, OUT=512, K_SLOTS=8, DK=64
// inputs: node_feats (64*256*512 f32), adj (64*8*256*256 f32), weight (512*512 f32), bias (512 f32)
// out: (64*256*512) f32

typedef __attribute__((ext_vector_type(8))) short short8;   // 8 bf16 (4 VGPRs) - MFMA A/B frag
typedef __attribute__((ext_vector_type(4))) float floatx4;  // MFMA C/D frag

__device__ __forceinline__ unsigned short f2bf(float f) {
    union { float f; unsigned u; } v; v.f = f;
    unsigned r = v.u + 0x7FFFu + ((v.u >> 16) & 1u);  // RNE
    return (unsigned short)(r >> 16);
}

// packed f32x2 -> bf16x2 (RNE); compiles to v_cvt_pk_bf16_f32 on gfx950
__device__ __forceinline__ unsigned pk2bf(float a, float b) {
    union { __hip_bfloat162 h; unsigned u; } cv;
    cv.h = __float22bfloat162_rn(make_float2(a, b));
    return cv.u;
}

// ---------------------------------------------------------------------------
// Pre-kernel: W (512x512, row-major [k][o]) -> Wt bf16 [o][k] (k contiguous)
// LDS-tiled transpose, 64x64 tiles, coalesced read AND write.
// ---------------------------------------------------------------------------
__global__ __launch_bounds__(256) void wt_kernel(const float* __restrict__ W,
                                                 unsigned short* __restrict__ Wt) {
    __shared__ unsigned short t_lds[64 * 66];  // [o][k], pad 66 -> 2-way (free)
    const int tile = blockIdx.x;      // 0..63 (8x8 tiles)
    const int k0 = (tile >> 3) * 64;
    const int o0 = (tile & 7) * 64;
    const int t = threadIdx.x;
    const int c = t & 63;             // coalesced dim
    const int rb = t >> 6;            // 0..3
#pragma unroll
    for (int i = 0; i < 16; ++i) {
        int r = i * 4 + rb;           // k-row within tile
        t_lds[c * 66 + r] = f2bf(W[(size_t)(k0 + r) * 512 + o0 + c]);
    }
    __syncthreads();
#pragma unroll
    for (int i = 0; i < 16; ++i) {
        int o_r = i * 4 + rb;         // o-row within tile
        Wt[(size_t)(o0 + o_r) * 512 + k0 + c] = t_lds[o_r * 66 + c];
    }
}

// ---------------------------------------------------------------------------
// Kernel 1: hT[((b*8+ks)*64+d)*256 + m] = bf16(relu(X@W + bias))
// 1D grid 1024 (64m x 128o tiles), block 256 (4 waves, each 64m x 32o).
// 4 blocks/CU resident -> barrier drains overlap across blocks.
// Swizzle: blocks sharing an X m-tile have ids == mod 8 -> same XCD L2.
// ---------------------------------------------------------------------------
__global__ __launch_bounds__(256, 4) void gemm_relu_kernel(
    const float* __restrict__ X, const unsigned short* __restrict__ Wt,
    const float* __restrict__ bias, unsigned short* __restrict__ hT) {
    // +8-short pad per 32-k row: row stride 40 shorts -> 2-way LDS conflicts (free)
    __shared__ unsigned short a_lds[64 * 40];    // 64 m x 32 k
    __shared__ unsigned short b_lds[128 * 40];   // 128 o x 32 k

    const int id = blockIdx.x;        // 0..1023
    const int r8 = id & 7;            // XCD residue
    const int ot = (id >> 3) & 3;     // o-tile (4 x 128)
    const int g  = id >> 5;           // 0..31
    const int m_tile = r8 + 8 * g;    // 0..255 (64-row m tiles)
    const int m_base = m_tile * 64;   // global M (b*256+m)
    const int o_base = ot * 128;      // global N (o)

    const int tid = threadIdx.x;
    const int lane = tid & 63, wid = tid >> 6;
    const int wn = wid * 32;          // wave o-offset within 128
    const int lrow = lane & 15, quad = lane >> 4;

    floatx4 acc[4][2];
    const floatx4 fzero = {0.f, 0.f, 0.f, 0.f};
#pragma unroll
    for (int i = 0; i < 4; ++i)
#pragma unroll
        for (int j = 0; j < 2; ++j) acc[i][j] = fzero;

    for (int kb = 0; kb < 16; ++kb) {
        const int k0 = kb * 32;
        // stage A tile: X fp32 -> bf16, 64 rows x 32 k (512 float4-chunks)
#pragma unroll
        for (int i = 0; i < 2; ++i) {
            int c4 = tid + i * 256;          // 0..511
            int rr = c4 >> 3;                // 0..63
            int cc = (c4 & 7) * 4;
            const float4 v = *(const float4*)(X + (size_t)(m_base + rr) * 512 + k0 + cc);
            unsigned p01 = pk2bf(v.x, v.y);
            unsigned p23 = pk2bf(v.z, v.w);
            unsigned* dst = (unsigned*)(a_lds + rr * 40 + cc);
            dst[0] = p01; dst[1] = p23;
        }
        // stage B tile: Wt bf16 [o][k], 128 rows x 32 k (1024 ushort4-chunks)
#pragma unroll
        for (int i = 0; i < 4; ++i) {
            int c4 = tid + i * 256;          // 0..1023
            int rr = c4 >> 3;                // 0..127
            int cc = (c4 & 7) * 4;
            *(ushort4*)(b_lds + rr * 40 + cc) =
                *(const ushort4*)(Wt + (size_t)(o_base + rr) * 512 + k0 + cc);
        }
        __syncthreads();

        short8 af[4], bfr[2];
#pragma unroll
        for (int i = 0; i < 4; ++i)
            af[i] = *(const short8*)(a_lds + (16 * i + lrow) * 40 + quad * 8);
#pragma unroll
        for (int j = 0; j < 2; ++j)
            bfr[j] = *(const short8*)(b_lds + (wn + 16 * j + lrow) * 40 + quad * 8);
#pragma unroll
        for (int i = 0; i < 4; ++i)
#pragma unroll
            for (int j = 0; j < 2; ++j)
                acc[i][j] = __builtin_amdgcn_mfma_f32_16x16x32_bf16(af[i], bfr[j], acc[i][j], 0, 0, 0);
        __syncthreads();
    }

    // epilogue: bias + relu + bf16, write transposed hT[d-row][m]
    const int b = m_tile >> 2;
    const int m_in_b0 = (m_tile & 3) * 64;
#pragma unroll
    for (int j = 0; j < 2; ++j) {
        int o = o_base + wn + 16 * j + lrow;  // C/D col = lane&15
        float bv = bias[o];
        int ks = o >> 6, d = o & 63;
        unsigned short* dst = hT + ((size_t)(b * 8 + ks) * 64 + d) * 256;
#pragma unroll
        for (int i = 0; i < 4; ++i) {
            int m = m_in_b0 + 16 * i + quad * 4;  // C/D row = quad*4+reg
            floatx4 c = acc[i][j];
            unsigned p01 = pk2bf(fmaxf(c.x + bv, 0.f), fmaxf(c.y + bv, 0.f));
            unsigned p23 = pk2bf(fmaxf(c.z + bv, 0.f), fmaxf(c.w + bv, 0.f));
            unsigned* d32 = (unsigned*)(dst + m);
            d32[0] = p01; d32[1] = p23;   // 8B store, 4 consecutive m
        }
    }
}

// ---------------------------------------------------------------------------
// Kernel 2: out[b,n,ks*64+d] = sum_m adj[b,ks,n,m] * hT[b,ks,d,m]
// 1D grid 1024, block 256 (4 waves, each 32n x 64d).
// adj streamed global->reg->bf16; 2-stage register pipeline: loads for mt+1
// are issued before the MFMAs of mt (cover ~L2/HBM latency with 4 waves/SIMD).
// ---------------------------------------------------------------------------
__global__ __launch_bounds__(256, 4) void agg_kernel(const float* __restrict__ adj,
                                                     const unsigned short* __restrict__ hT,
                                                     float* __restrict__ out) {
    const int id = blockIdx.x;        // 0..1023
    const int r8 = id & 7;
    const int half = (id >> 3) & 1;
    const int q = id >> 4;            // 0..63
    const int bk = r8 + 8 * q;        // b*8+ks, 0..511

    const int tid = threadIdx.x;
    const int lane = tid & 63, wid = tid >> 6;
    const int b = bk >> 3, ks = bk & 7;
    const int lrow = lane & 15, quad = lane >> 4;
    const int n0 = half * 128 + wid * 32;

    const float* A0 = adj + (size_t)bk * 65536 + (size_t)(n0 + lrow) * 256;       // frag i=0 row
    const float* A1 = A0 + 16 * 256;                                              // frag i=1 row
    const unsigned short* Bh = hT + (size_t)bk * 16384 + (size_t)lrow * 256;      // + j*16*256

    floatx4 acc[2][4];
    const floatx4 fzero = {0.f, 0.f, 0.f, 0.f};
#pragma unroll
    for (int i = 0; i < 2; ++i)
#pragma unroll
        for (int j = 0; j < 4; ++j) acc[i][j] = fzero;

    short8 afc[2], bfc[4], afn[2], bfn[4];

    auto load_frags = [&](int mo, short8* af, short8* bf) {
        const float* srcs[2] = {A0 + mo, A1 + mo};
#pragma unroll
        for (int i = 0; i < 2; ++i) {
            float4 v0 = *(const float4*)(srcs[i]);
            float4 v1 = *(const float4*)(srcs[i] + 4);
            union { short8 s; unsigned u[4]; } t;
            t.u[0] = pk2bf(v0.x, v0.y);
            t.u[1] = pk2bf(v0.z, v0.w);
            t.u[2] = pk2bf(v1.x, v1.y);
            t.u[3] = pk2bf(v1.z, v1.w);
            af[i] = t.s;
        }
#pragma unroll
        for (int j = 0; j < 4; ++j)
            bf[j] = *(const short8*)(Bh + j * 16 * 256 + mo);  // 16B aligned
    };

    auto mfma8 = [&](short8* af, short8* bf) {
#pragma unroll
        for (int i = 0; i < 2; ++i)
#pragma unroll
            for (int j = 0; j < 4; ++j)
                acc[i][j] = __builtin_amdgcn_mfma_f32_16x16x32_bf16(af[i], bf[j], acc[i][j], 0, 0, 0);
    };

    int mo = quad * 8;                 // lane k-offset; +32 per mt step
    load_frags(mo, afc, bfc);
#pragma unroll
    for (int t = 0; t < 4; ++t) {      // 8 mt-iters, unrolled x2
        load_frags(mo + 32, afn, bfn); // prefetch mt=2t+1
        mfma8(afc, bfc);               // compute mt=2t
        if (t < 3) load_frags(mo + 64, afc, bfc);  // prefetch mt=2t+2
        mfma8(afn, bfn);               // compute mt=2t+1
        mo += 64;
    }

    // epilogue: C/D layout col=lane&15 (d), row=quad*4+reg (n)
#pragma unroll
    for (int i = 0; i < 2; ++i) {
#pragma unroll
        for (int j = 0; j < 4; ++j) {
            int n = n0 + 16 * i + quad * 4;
            int d = 16 * j + lrow;
            float* dst = out + ((size_t)b * 256 + n) * 512 + ks * 64 + d;
            floatx4 c = acc[i][j];
            dst[0 * 512] = c.x;
            dst[1 * 512] = c.y;
            dst[2 * 512] = c.z;
            dst[3 * 512] = c.w;
        }
    }
}

// ---------------------------------------------------------------------------
extern "C" void kernel_launch(void* const* d_in, const int* in_sizes, int n_in,
                              void* d_out, int out_size, void* d_ws, size_t ws_size,
                              hipStream_t stream) {
    const float* X    = (const float*)d_in[0];  // node_feats
    const float* adj  = (const float*)d_in[1];  // adj
    const float* W    = (const float*)d_in[2];  // weight
    const float* bias = (const float*)d_in[3];  // bias
    float* out = (float*)d_out;

    // workspace layout: hT bf16 [64*8*64*256] (16 MiB), then Wt bf16 [512*512]
    unsigned short* hT = (unsigned short*)d_ws;
    unsigned short* Wt = hT + (size_t)64 * 8 * 64 * 256;

    wt_kernel<<<64, 256, 0, stream>>>(W, Wt);
    gemm_relu_kernel<<<1024, 256, 0, stream>>>(X, Wt, bias, hT);
    agg_kernel<<<1024, 256, 0, stream>>>(adj, hT, out);
}

// Round 5
// 250.310 us; speedup vs baseline: 1.0476x; 1.0476x over previous
//
#include <hip/hip_runtime.h>
#include <hip/hip_bf16.h>

// Problem constants
// B=64, N=256, IN=512, OUT=512, K_SLOTS=8, DK=64
// inputs: node_feats (64*256*512 f32), adj (64*8*256*256 f32), weight (512*512 f32), bias (512 f32)
// out: (64*256*512) f32

typedef __attribute__((ext_vector_type(8))) short short8;   // 8 bf16 (4 VGPRs) - MFMA A/B frag
typedef __attribute__((ext_vector_type(4))) float floatx4;  // MFMA C/D frag

__device__ __forceinline__ unsigned short f2bf(float f) {
    union { float f; unsigned u; } v; v.f = f;
    unsigned r = v.u + 0x7FFFu + ((v.u >> 16) & 1u);  // RNE
    return (unsigned short)(r >> 16);
}

// packed f32x2 -> bf16x2 (RNE); compiles to v_cvt_pk_bf16_f32 on gfx950
__device__ __forceinline__ unsigned pk2bf(float a, float b) {
    union { __hip_bfloat162 h; unsigned u; } cv;
    cv.h = __float22bfloat162_rn(make_float2(a, b));
    return cv.u;
}

// ---------------------------------------------------------------------------
// Pre-kernel: W (512x512, row-major [k][o]) -> Wt bf16 [o][k] (k contiguous)
// LDS-tiled transpose, 64x64 tiles, coalesced read AND write.
// ---------------------------------------------------------------------------
__global__ __launch_bounds__(256) void wt_kernel(const float* __restrict__ W,
                                                 unsigned short* __restrict__ Wt) {
    __shared__ unsigned short t_lds[64 * 66];  // [o][k], pad 66 -> 2-way (free)
    const int tile = blockIdx.x;      // 0..63 (8x8 tiles)
    const int k0 = (tile >> 3) * 64;
    const int o0 = (tile & 7) * 64;
    const int t = threadIdx.x;
    const int c = t & 63;             // coalesced dim
    const int rb = t >> 6;            // 0..3
#pragma unroll
    for (int i = 0; i < 16; ++i) {
        int r = i * 4 + rb;           // k-row within tile
        t_lds[c * 66 + r] = f2bf(W[(size_t)(k0 + r) * 512 + o0 + c]);
    }
    __syncthreads();
#pragma unroll
    for (int i = 0; i < 16; ++i) {
        int o_r = i * 4 + rb;         // o-row within tile
        Wt[(size_t)(o0 + o_r) * 512 + k0 + c] = t_lds[o_r * 66 + c];
    }
}

// ---------------------------------------------------------------------------
// Fused kernel: one block per (b, ks).
//   Stage 1: h_slice[256 m][64 d] = relu(X[b] @ Wt[ks*64.., :]^T + bias)  (MFMA, LDS-staged)
//            -> written to LDS as hT [64 d][256 m] bf16 (no global round-trip)
//   Stage 2: out[b, n, ks*64+d] = sum_m adj[b,ks,n,m] * hT[d][m]          (MFMA)
// Grid 512 (id: b = id&63, ks = id>>6 -> all 8 ks-blocks of a b on one XCD,
// X[b] fetched from HBM once, L2-served 7x). Block 512 threads = 8 waves,
// 2 blocks/CU (LDS 33 KB via union), 4 waves/SIMD.
// ---------------------------------------------------------------------------
__global__ __launch_bounds__(512, 4) void fused_kernel(
    const float* __restrict__ X, const unsigned short* __restrict__ Wt,
    const float* __restrict__ bias, const float* __restrict__ adj,
    float* __restrict__ out) {
    __shared__ union {
        struct {
            unsigned short a[256 * 40];  // X tile: 256 m x 32 k bf16, pad 40
            unsigned short w[64 * 40];   // W slice tile: 64 o x 32 k bf16
        } s1;
        unsigned short ht[64 * 264];     // hT: 64 d x 256 m bf16, pad 264
    } lds;

    const int id = blockIdx.x;        // 0..511
    const int b = id & 63;            // same-b blocks == mod 8 -> same XCD
    const int ks = id >> 6;

    const int tid = threadIdx.x;
    const int lane = tid & 63, w = tid >> 6;   // wave 0..7
    const int lrow = lane & 15, quad = lane >> 4;

    const float* Xb = X + (size_t)b * 256 * 512;
    const unsigned short* Wslice = Wt + (size_t)ks * 64 * 512;  // [o_local][k]

    // ---------------- Stage 1: X[b] @ W-slice -> acc1 ----------------
    floatx4 acc1[2][4];               // m-frags (wave's 32 m) x o-frags (64 o)
    const floatx4 fzero = {0.f, 0.f, 0.f, 0.f};
#pragma unroll
    for (int i = 0; i < 2; ++i)
#pragma unroll
        for (int j = 0; j < 4; ++j) acc1[i][j] = fzero;

    for (int kb = 0; kb < 16; ++kb) {
        const int k0 = kb * 32;
        // stage A: 256 m x 32 k = 2048 float4-chunks / 512 threads
#pragma unroll
        for (int i = 0; i < 4; ++i) {
            int c4 = tid + i * 512;          // 0..2047
            int rr = c4 >> 3;                // 0..255
            int cc = (c4 & 7) * 4;
            const float4 v = *(const float4*)(Xb + (size_t)rr * 512 + k0 + cc);
            unsigned p01 = pk2bf(v.x, v.y);
            unsigned p23 = pk2bf(v.z, v.w);
            unsigned* dst = (unsigned*)(lds.s1.a + rr * 40 + cc);
            dst[0] = p01; dst[1] = p23;
        }
        // stage W: 64 o x 32 k = 512 ushort4-chunks / 512 threads
        {
            int rr = tid >> 3;               // 0..63
            int cc = (tid & 7) * 4;
            *(ushort4*)(lds.s1.w + rr * 40 + cc) =
                *(const ushort4*)(Wslice + (size_t)rr * 512 + k0 + cc);
        }
        __syncthreads();

        short8 af[2], bfr[4];
#pragma unroll
        for (int i = 0; i < 2; ++i)
            af[i] = *(const short8*)(lds.s1.a + (w * 32 + 16 * i + lrow) * 40 + quad * 8);
#pragma unroll
        for (int j = 0; j < 4; ++j)
            bfr[j] = *(const short8*)(lds.s1.w + (16 * j + lrow) * 40 + quad * 8);
#pragma unroll
        for (int i = 0; i < 2; ++i)
#pragma unroll
            for (int j = 0; j < 4; ++j)
                acc1[i][j] = __builtin_amdgcn_mfma_f32_16x16x32_bf16(af[i], bfr[j], acc1[i][j], 0, 0, 0);
        __syncthreads();
    }

    // ---------------- Stage 1 epilogue: bias+relu+bf16 -> lds.ht[d][m] ----------------
#pragma unroll
    for (int j = 0; j < 4; ++j) {
        int d = 16 * j + lrow;               // C/D col = lane&15
        float bv = bias[ks * 64 + d];
#pragma unroll
        for (int i = 0; i < 2; ++i) {
            int m = w * 32 + 16 * i + quad * 4;  // C/D row = quad*4+reg
            floatx4 c = acc1[i][j];
            unsigned p01 = pk2bf(fmaxf(c.x + bv, 0.f), fmaxf(c.y + bv, 0.f));
            unsigned p23 = pk2bf(fmaxf(c.z + bv, 0.f), fmaxf(c.w + bv, 0.f));
            unsigned* d32 = (unsigned*)(lds.ht + d * 264 + m);
            d32[0] = p01; d32[1] = p23;      // 8B store, 4 consecutive m
        }
    }
    __syncthreads();

    // ---------------- Stage 2: adj[b,ks] @ hT -> out ----------------
    const float* A = adj + (size_t)id * 65536;   // adj[b][ks] = adj[(b*8+ks)]... careful: layout is [b][ks]
    // adj layout: adj[b][k][n][m] -> offset ((b*8+ks)*256 + n)*256 + m
    const float* Abase = adj + ((size_t)(b * 8 + ks)) * 65536;
    (void)A;

    floatx4 acc2[2][4];
#pragma unroll
    for (int i = 0; i < 2; ++i)
#pragma unroll
        for (int j = 0; j < 4; ++j) acc2[i][j] = fzero;

    const float* A0 = Abase + (size_t)(w * 32 + lrow) * 256;       // frag i=0 row
    const float* A1 = A0 + 16 * 256;                               // frag i=1 row

#pragma unroll
    for (int mt = 0; mt < 8; ++mt) {
        const int m0 = mt * 32 + quad * 8;
        short8 af[2], bfr[4];
#pragma unroll
        for (int i = 0; i < 2; ++i) {
            const float* src = (i == 0 ? A0 : A1) + m0;
            float4 v0 = *(const float4*)src;
            float4 v1 = *(const float4*)(src + 4);
            union { short8 s; unsigned u[4]; } t;
            t.u[0] = pk2bf(v0.x, v0.y);
            t.u[1] = pk2bf(v0.z, v0.w);
            t.u[2] = pk2bf(v1.x, v1.y);
            t.u[3] = pk2bf(v1.z, v1.w);
            af[i] = t.s;
        }
#pragma unroll
        for (int j = 0; j < 4; ++j)
            bfr[j] = *(const short8*)(lds.ht + (16 * j + lrow) * 264 + m0);
#pragma unroll
        for (int i = 0; i < 2; ++i)
#pragma unroll
            for (int j = 0; j < 4; ++j)
                acc2[i][j] = __builtin_amdgcn_mfma_f32_16x16x32_bf16(af[i], bfr[j], acc2[i][j], 0, 0, 0);
    }

    // epilogue: C/D layout col=lane&15 (d), row=quad*4+reg (n)
#pragma unroll
    for (int i = 0; i < 2; ++i) {
#pragma unroll
        for (int j = 0; j < 4; ++j) {
            int n = w * 32 + 16 * i + quad * 4;
            int d = 16 * j + lrow;
            float* dst = out + ((size_t)b * 256 + n) * 512 + ks * 64 + d;
            floatx4 c = acc2[i][j];
            dst[0 * 512] = c.x;
            dst[1 * 512] = c.y;
            dst[2 * 512] = c.z;
            dst[3 * 512] = c.w;
        }
    }
}

// ---------------------------------------------------------------------------
extern "C" void kernel_launch(void* const* d_in, const int* in_sizes, int n_in,
                              void* d_out, int out_size, void* d_ws, size_t ws_size,
                              hipStream_t stream) {
    const float* X    = (const float*)d_in[0];  // node_feats
    const float* adj  = (const float*)d_in[1];  // adj
    const float* W    = (const float*)d_in[2];  // weight
    const float* bias = (const float*)d_in[3];  // bias
    float* out = (float*)d_out;

    // workspace: Wt bf16 [512*512] only
    unsigned short* Wt = (unsigned short*)d_ws;

    wt_kernel<<<64, 256, 0, stream>>>(W, Wt);
    fused_kernel<<<512, 512, 0, stream>>>(X, Wt, bias, adj, out);
}